// Round 7
// baseline (132.696 us; speedup 1.0000x reference)
//
#include <hip/hip_runtime.h>
#include <hip/hip_cooperative_groups.h>

namespace cg = cooperative_groups;

#define L2E 1.44269504088896340736f

typedef __attribute__((ext_vector_type(8))) short bf16x8;
typedef __attribute__((ext_vector_type(4))) float f32x4;

__device__ __forceinline__ unsigned bf16_rne(float v) {
    unsigned x = __float_as_uint(v);
    return (x + 0x7FFFu + ((x >> 16) & 1u)) >> 16;
}

__device__ __forceinline__ void cvt_hilo4(float4 v, uint2* hi, uint2* lo) {
    unsigned h0 = bf16_rne(v.x), h1 = bf16_rne(v.y), h2 = bf16_rne(v.z), h3 = bf16_rne(v.w);
    float f0 = __uint_as_float(h0 << 16), f1 = __uint_as_float(h1 << 16);
    float f2 = __uint_as_float(h2 << 16), f3 = __uint_as_float(h3 << 16);
    unsigned l0 = bf16_rne(v.x - f0), l1 = bf16_rne(v.y - f1);
    unsigned l2 = bf16_rne(v.z - f2), l3 = bf16_rne(v.w - f3);
    hi->x = h0 | (h1 << 16); hi->y = h2 | (h3 << 16);
    lo->x = l0 | (l1 << 16); lo->y = l2 | (l3 << 16);
}

// Fused GAT: phase1 = proj (h, e) ; grid sync ; phase2 = softmax + PV.
// 256 blocks x 512 threads (1 block/CU), block owns 16 rows for BOTH phases.
__global__ __launch_bounds__(512) void fused_gat(
    const float* __restrict__ x, const int* __restrict__ adj,
    const int* __restrict__ adjin, const int* __restrict__ adjout,
    const float* __restrict__ W, const float* __restrict__ A,
    const float* __restrict__ ab,
    unsigned short* __restrict__ hTg, float* __restrict__ edstT,
    float* __restrict__ out)
{
    __shared__ unsigned short xh[16 * 136], xl[16 * 136];
    __shared__ unsigned short wh[64 * 136], wl[64 * 136];
    __shared__ unsigned short Ach[32 * 72], Acl[32 * 72];
    __shared__ unsigned short hsh[16 * 72], hsl[16 * 72];
    __shared__ float esl[16 * 12];
    __shared__ unsigned short Ph[16 * 264];
    __shared__ float red[4 * 272];          // [nt][m][ml] pitch 17 — 16 rows x 16 cols

    const int t = threadIdx.x;
    const int row0 = blockIdx.x * 16;       // flat row over (B*N)
    const int b = row0 >> 8;
    const int ibase = row0 & 255;
    const int lane = t & 63;
    const int wv = t >> 6;                  // 0..7

    // ---- phase 0: mask prefetch for this thread's phase-2 slice ----
    const int g = lane >> 5;                // row parity within wave
    const int q = lane & 31;                // j-block: j = 8q..8q+7
    const int rloc = wv * 2 + g;            // 0..15
    const long gi = (long)(row0 + rloc);
    int4 Ma0, Ma1, Mb0, Mb1, Mc0, Mc1;
    {
        const int4* mp0 = (const int4*)(adj    + gi * 256 + 8 * q);
        const int4* mp1 = (const int4*)(adjin  + gi * 256 + 8 * q);
        const int4* mp2 = (const int4*)(adjout + gi * 256 + 8 * q);
        Ma0 = mp0[0]; Ma1 = mp0[1];
        Mb0 = mp1[0]; Mb1 = mp1[1];
        Mc0 = mp2[0]; Mc1 = mp2[1];
    }

    // ---- phase 1: stage + convert x, W, Acat ----
    {
        int q4 = t;                          // 512 float4 groups (16x128)
        int r = q4 >> 5, c = (q4 & 31) * 4;
        float4 v = *(const float4*)&x[row0 * 128 + 4 * q4];
        uint2 hi, lo; cvt_hilo4(v, &hi, &lo);
        *(uint2*)&xh[r * 136 + c] = hi;
        *(uint2*)&xl[r * 136 + c] = lo;
    }
#pragma unroll
    for (int p = 0; p < 4; ++p) {
        int q4 = t + 512 * p;                // 2048 groups (64x128)
        int r = q4 >> 5, c = (q4 & 31) * 4;
        float4 v = *(const float4*)&W[4 * q4];
        uint2 hi, lo; cvt_hilo4(v, &hi, &lo);
        *(uint2*)&wh[r * 136 + c] = hi;
        *(uint2*)&wl[r * 136 + c] = lo;
    }
    {
        int q4 = t;                          // 512 groups (32x64, 24 valid)
        int n = q4 >> 4, d = (q4 & 15) * 4;
        float4 v = make_float4(0.f, 0.f, 0.f, 0.f);
        if (n < 24) {
            int nn = (n < 12) ? n : n - 12;
            v = *(const float4*)&A[nn * 128 + ((n < 12) ? 0 : 64) + d];
        }
        uint2 hi, lo; cvt_hilo4(v, &hi, &lo);
        *(uint2*)&Ach[n * 72 + d] = hi;
        *(uint2*)&Acl[n * 72 + d] = lo;
    }
    __syncthreads();

    const int ml = lane & 15, kb = lane >> 4;

    // h-MFMA: h[16][64] = x[16][128] @ W[64][128]^T (waves 0..3, hi/lo 3-term)
    if (wv < 4) {
        f32x4 acc = {0.f, 0.f, 0.f, 0.f};
#pragma unroll
        for (int ks = 0; ks < 4; ++ks) {
            const int ko = ks * 32 + kb * 8;
            bf16x8 axh = *(const bf16x8*)&xh[ml * 136 + ko];
            bf16x8 axl = *(const bf16x8*)&xl[ml * 136 + ko];
            bf16x8 bwh = *(const bf16x8*)&wh[(wv * 16 + ml) * 136 + ko];
            bf16x8 bwl = *(const bf16x8*)&wl[(wv * 16 + ml) * 136 + ko];
            acc = __builtin_amdgcn_mfma_f32_16x16x32_bf16(axh, bwh, acc, 0, 0, 0);
            acc = __builtin_amdgcn_mfma_f32_16x16x32_bf16(axh, bwl, acc, 0, 0, 0);
            acc = __builtin_amdgcn_mfma_f32_16x16x32_bf16(axl, bwh, acc, 0, 0, 0);
        }
#pragma unroll
        for (int r = 0; r < 4; ++r) {
            const int m = kb * 4 + r, c = wv * 16 + ml;
            unsigned hi = bf16_rne(acc[r]);
            float hif = __uint_as_float(hi << 16);
            hsh[m * 72 + c] = (unsigned short)hi;
            hsl[m * 72 + c] = (unsigned short)bf16_rne(acc[r] - hif);
        }
    }
    __syncthreads();

    // e-MFMA (waves 0,1): e[16][24] = h @ Acat^T ; esrc->LDS, edstT->global
    if (wv < 2) {
        f32x4 e4 = {0.f, 0.f, 0.f, 0.f};
#pragma unroll
        for (int ks = 0; ks < 2; ++ks) {
            const int ko = ks * 32 + kb * 8;
            bf16x8 ah = *(const bf16x8*)&hsh[ml * 72 + ko];
            bf16x8 al = *(const bf16x8*)&hsl[ml * 72 + ko];
            bf16x8 bh = *(const bf16x8*)&Ach[(wv * 16 + ml) * 72 + ko];
            bf16x8 bl = *(const bf16x8*)&Acl[(wv * 16 + ml) * 72 + ko];
            e4 = __builtin_amdgcn_mfma_f32_16x16x32_bf16(ah, bh, e4, 0, 0, 0);
            e4 = __builtin_amdgcn_mfma_f32_16x16x32_bf16(ah, bl, e4, 0, 0, 0);
            e4 = __builtin_amdgcn_mfma_f32_16x16x32_bf16(al, bh, e4, 0, 0, 0);
        }
#pragma unroll
        for (int r = 0; r < 4; ++r) {
            const int m = kb * 4 + r, n = wv * 16 + ml;
            if (n < 12)
                esl[m * 12 + n] = (e4[r] + ab[n]) * L2E;            // pre-bias + pre-scale
            else if (n < 24)
                edstT[(b * 12 + (n - 12)) * 256 + ibase + m] = e4[r] * L2E;
        }
    } else {
        // hT write packed (uint = 2 bf16 along j): threads 128..511 cover 512 words
        int e2 = t - 128;                    // 0..383
#pragma unroll
        for (int rep = 0; rep < 2; ++rep) {
            int w2 = e2 + 384 * rep;
            if (w2 < 512) {
                int d = w2 >> 3, j2 = (w2 & 7) * 2;
                unsigned lo16 = hsh[j2 * 72 + d], hi16 = hsh[(j2 + 1) * 72 + d];
                *(unsigned*)&hTg[(b * 64 + d) * 256 + ibase + j2] = lo16 | (hi16 << 16);
            }
        }
    }

    __threadfence();           // release hTg/edstT device-wide
    cg::this_grid().sync();    // cross-block dependency: hTg/edstT of same batch
    __threadfence();           // acquire

    // ---- phase 2: masked 12-head softmax (no-max, pre-scaled) ----
    float fm[3][8];
    fm[0][0] = (float)Ma0.x; fm[0][1] = (float)Ma0.y; fm[0][2] = (float)Ma0.z; fm[0][3] = (float)Ma0.w;
    fm[0][4] = (float)Ma1.x; fm[0][5] = (float)Ma1.y; fm[0][6] = (float)Ma1.z; fm[0][7] = (float)Ma1.w;
    fm[1][0] = (float)Mb0.x; fm[1][1] = (float)Mb0.y; fm[1][2] = (float)Mb0.z; fm[1][3] = (float)Mb0.w;
    fm[1][4] = (float)Mb1.x; fm[1][5] = (float)Mb1.y; fm[1][6] = (float)Mb1.z; fm[1][7] = (float)Mb1.w;
    fm[2][0] = (float)Mc0.x; fm[2][1] = (float)Mc0.y; fm[2][2] = (float)Mc0.z; fm[2][3] = (float)Mc0.w;
    fm[2][4] = (float)Mc1.x; fm[2][5] = (float)Mc1.y; fm[2][6] = (float)Mc1.z; fm[2][7] = (float)Mc1.w;

    const float4* ep = (const float4*)&esl[rloc * 12];
    const float4 eA = ep[0], eB = ep[1], eC = ep[2];
    const float e0[12] = {eA.x, eA.y, eA.z, eA.w, eB.x, eB.y, eB.z, eB.w, eC.x, eC.y, eC.z, eC.w};

    float Pacc[8] = {0.f, 0.f, 0.f, 0.f, 0.f, 0.f, 0.f, 0.f};
#pragma unroll
    for (int hh = 0; hh < 12; ++hh) {
        const int grp = hh >> 2;
        const float4* evp = (const float4*)(edstT + (size_t)(b * 12 + hh) * 256 + 8 * q);
        const float4 ev0 = evp[0], ev1 = evp[1];
        const float evv[8] = {ev0.x, ev0.y, ev0.z, ev0.w, ev1.x, ev1.y, ev1.z, ev1.w};
        float p[8], s = 0.f;
#pragma unroll
        for (int k = 0; k < 8; ++k) {
            float v = e0[hh] + evv[k];
            v = fmaxf(v, 0.01f * v);                       // leaky in log2 domain
            p[k] = __builtin_amdgcn_exp2f(v) * fm[grp][k];
            s += p[k];
        }
#pragma unroll
        for (int off = 16; off >= 1; off >>= 1)
            s += __shfl_xor(s, off);                       // 32-lane group reduce
        const float rinv = __builtin_amdgcn_rcpf(s);
#pragma unroll
        for (int k = 0; k < 8; ++k)
            Pacc[k] += p[k] * rinv;
    }
    {
        uint4 pk;
        pk.x = bf16_rne(Pacc[0]) | (bf16_rne(Pacc[1]) << 16);
        pk.y = bf16_rne(Pacc[2]) | (bf16_rne(Pacc[3]) << 16);
        pk.z = bf16_rne(Pacc[4]) | (bf16_rne(Pacc[5]) << 16);
        pk.w = bf16_rne(Pacc[6]) | (bf16_rne(Pacc[7]) << 16);
        *(uint4*)&Ph[rloc * 264 + 8 * q] = pk;
    }
    __syncthreads();

    // ---- PV: out[16][64] = P[16][256] x hT^T ; K split across wave pairs ----
    const int nt = wv & 3, kh = wv >> 2;
    const unsigned short* hTb = hTg + ((size_t)(b * 64 + nt * 16 + ml)) * 256;
    f32x4 acc = {0.f, 0.f, 0.f, 0.f};
#pragma unroll
    for (int ks = 0; ks < 4; ++ks) {
        const int ko = kh * 128 + ks * 32 + kb * 8;
        bf16x8 bh = *(const bf16x8*)&hTb[ko];
        bf16x8 ah = *(const bf16x8*)&Ph[ml * 264 + ko];
        acc = __builtin_amdgcn_mfma_f32_16x16x32_bf16(ah, bh, acc, 0, 0, 0);
    }
    if (kh == 1) {
#pragma unroll
        for (int r = 0; r < 4; ++r)
            red[nt * 272 + (kb * 4 + r) * 17 + ml] = acc[r];
    }
    __syncthreads();
    if (kh == 0) {
#pragma unroll
        for (int r = 0; r < 4; ++r) {
            const int m = kb * 4 + r;       // 0..15
            const float v = (acc[r] + red[nt * 272 + m * 17 + ml]) * (1.0f / 12.0f);
            out[(size_t)(row0 + m) * 64 + nt * 16 + ml] = v;
        }
    }
}

extern "C" void kernel_launch(void* const* d_in, const int* in_sizes, int n_in,
                              void* d_out, int out_size, void* d_ws, size_t ws_size,
                              hipStream_t stream) {
    const float* x    = (const float*)d_in[0];
    const int*   adj  = (const int*)d_in[1];
    const int*   adji = (const int*)d_in[2];
    const int*   adjo = (const int*)d_in[3];
    const float* W    = (const float*)d_in[4];
    const float* A    = (const float*)d_in[5];
    const float* ab   = (const float*)d_in[6];
    float* out = (float*)d_out;

    unsigned short* hTg = (unsigned short*)d_ws;              // 512 KB
    float* edstT = (float*)((char*)d_ws + (512 << 10));       // 192 KB

    void* args[] = {(void*)&x, (void*)&adj, (void*)&adji, (void*)&adjo,
                    (void*)&W, (void*)&A, (void*)&ab,
                    (void*)&hTg, (void*)&edstT, (void*)&out};
    hipLaunchCooperativeKernel((const void*)fused_gat, dim3(256), dim3(512),
                               args, 0, stream);
}

// Round 8
// 23.530 us; speedup vs baseline: 5.6394x; 5.6394x over previous
//
#include <hip/hip_runtime.h>

#define L2E 1.44269504088896340736f

typedef __attribute__((ext_vector_type(8))) short bf16x8;
typedef __attribute__((ext_vector_type(4))) float f32x4;

__device__ __forceinline__ unsigned bf16_rne(float v) {
    unsigned x = __float_as_uint(v);
    return (x + 0x7FFFu + ((x >> 16) & 1u)) >> 16;
}

__device__ __forceinline__ void cvt_hilo4(float4 v, uint2* hi, uint2* lo) {
    unsigned h0 = bf16_rne(v.x), h1 = bf16_rne(v.y), h2 = bf16_rne(v.z), h3 = bf16_rne(v.w);
    float f0 = __uint_as_float(h0 << 16), f1 = __uint_as_float(h1 << 16);
    float f2 = __uint_as_float(h2 << 16), f3 = __uint_as_float(h3 << 16);
    unsigned l0 = bf16_rne(v.x - f0), l1 = bf16_rne(v.y - f1);
    unsigned l2 = bf16_rne(v.z - f2), l3 = bf16_rne(v.w - f3);
    hi->x = h0 | (h1 << 16); hi->y = h2 | (h3 << 16);
    lo->x = l0 | (l1 << 16); lo->y = l2 | (l3 << 16);
}

// Single-kernel fused GAT, NO grid sync: each block (b, itile) redundantly
// computes h[b] (bf16 hi into LDS hT) + e_dstT[b] (LDS) via MFMA in 8 chunks
// of 32 j-rows, then runs masked 12-head softmax + MFMA PV for its 16 rows.
// 256 blocks x 512 threads, ~127 KB LDS -> 1 block/CU.
__global__ __launch_bounds__(512, 2) void fused_gat(
    const float* __restrict__ x, const int* __restrict__ adj,
    const int* __restrict__ adjin, const int* __restrict__ adjout,
    const float* __restrict__ W, const float* __restrict__ A,
    const float* __restrict__ ab,
    float* __restrict__ out)
{
    __shared__ unsigned short wh[64 * 136], wl[64 * 136];      // W hi/lo
    __shared__ unsigned short xh[32 * 136], xl[32 * 136];      // x chunk hi/lo
    __shared__ unsigned short Ach[32 * 72], Acl[32 * 72];      // [A1;A2] hi/lo
    __shared__ unsigned short hsh[32 * 72], hsl[32 * 72];      // h chunk hi/lo
    __shared__ unsigned short hT[64 * 264];                    // h^T bf16 [d][j] full batch
    __shared__ float edT[12 * 260];                            // e_dstT * L2E [hh][j]
    __shared__ float esl[16 * 12];                             // own-row e_src (pre-bias*L2E)
    __shared__ unsigned short Ph[16 * 264];                    // P bf16 [own row][j]
    __shared__ float red[4 * 272];                             // PV cross-wave K-reduce

    const int t = threadIdx.x;
    const int b = blockIdx.x >> 4;
    const int itile = blockIdx.x & 15;
    const int i0 = itile * 16;               // own local rows [i0, i0+16)
    const int lane = t & 63;
    const int wv = t >> 6;                   // 0..7
    const int g = lane >> 5;                 // row parity
    const int q = lane & 31;                 // j-block: j = 8q..8q+7
    const int rloc = wv * 2 + g;             // 0..15 own-row index
    const long gi = (long)(b * 256 + i0 + rloc);
    const int ml = lane & 15, kb = lane >> 4;

    // ---- phase 0: mask prefetch (used only in phase 2) ----
    int4 Ma0, Ma1, Mb0, Mb1, Mc0, Mc1;
    {
        const int4* mp0 = (const int4*)(adj    + gi * 256 + 8 * q);
        const int4* mp1 = (const int4*)(adjin  + gi * 256 + 8 * q);
        const int4* mp2 = (const int4*)(adjout + gi * 256 + 8 * q);
        Ma0 = mp0[0]; Ma1 = mp0[1];
        Mb0 = mp1[0]; Mb1 = mp1[1];
        Mc0 = mp2[0]; Mc1 = mp2[1];
    }

    // x chunk-0 preload (2 float4/thread)
    float4 xv0, xv1;
    {
        const size_t xb = (size_t)b * 256 * 128;
        xv0 = *(const float4*)&x[xb + (size_t)(t >> 5) * 128 + (t & 31) * 4];
        xv1 = *(const float4*)&x[xb + (size_t)((t + 512) >> 5) * 128 + (t & 31) * 4];
    }

    // ---- stage W (64x128) and Acat (24x64, padded to 32) ----
#pragma unroll
    for (int p = 0; p < 4; ++p) {
        int q4 = t + 512 * p;                // 0..2047
        int r = q4 >> 5, c4 = (q4 & 31) * 4;
        float4 v = *(const float4*)&W[4 * q4];
        uint2 hi, lo; cvt_hilo4(v, &hi, &lo);
        *(uint2*)&wh[r * 136 + c4] = hi;
        *(uint2*)&wl[r * 136 + c4] = lo;
    }
    {
        int n = t >> 4, d = (t & 15) * 4;    // 512 groups (32x64)
        float4 v = make_float4(0.f, 0.f, 0.f, 0.f);
        if (n < 24) {
            int nn = (n < 12) ? n : n - 12;
            v = *(const float4*)&A[nn * 128 + ((n < 12) ? 0 : 64) + d];
        }
        uint2 hi, lo; cvt_hilo4(v, &hi, &lo);
        *(uint2*)&Ach[n * 72 + d] = hi;
        *(uint2*)&Acl[n * 72 + d] = lo;
    }

    // ---- phase 1: 8 chunks of 32 j-rows: h chunk + hT + e chunk ----
    for (int c = 0; c < 8; ++c) {
        // [A] write staged x regs -> LDS
        {
            int r0 = t >> 5, c4 = (t & 31) * 4;
            uint2 hi, lo; cvt_hilo4(xv0, &hi, &lo);
            *(uint2*)&xh[r0 * 136 + c4] = hi;
            *(uint2*)&xl[r0 * 136 + c4] = lo;
            int r1 = (t + 512) >> 5;
            cvt_hilo4(xv1, &hi, &lo);
            *(uint2*)&xh[r1 * 136 + c4] = hi;
            *(uint2*)&xl[r1 * 136 + c4] = lo;
        }
        __syncthreads();                     // xh ready (and W/Acat on c=0)

        // [B] h-MFMA: h[32][64] = x_chunk[32][128] @ W^T  (8 waves: 2M x 4N)
        const int mt = wv & 1, nt2 = wv >> 1;
        f32x4 hacc = {0.f, 0.f, 0.f, 0.f};
#pragma unroll
        for (int ks = 0; ks < 4; ++ks) {
            const int ko = ks * 32 + kb * 8;
            bf16x8 axh = *(const bf16x8*)&xh[(mt * 16 + ml) * 136 + ko];
            bf16x8 axl = *(const bf16x8*)&xl[(mt * 16 + ml) * 136 + ko];
            bf16x8 bwh = *(const bf16x8*)&wh[(nt2 * 16 + ml) * 136 + ko];
            bf16x8 bwl = *(const bf16x8*)&wl[(nt2 * 16 + ml) * 136 + ko];
            hacc = __builtin_amdgcn_mfma_f32_16x16x32_bf16(axh, bwh, hacc, 0, 0, 0);
            hacc = __builtin_amdgcn_mfma_f32_16x16x32_bf16(axh, bwl, hacc, 0, 0, 0);
            hacc = __builtin_amdgcn_mfma_f32_16x16x32_bf16(axl, bwh, hacc, 0, 0, 0);
        }
        __syncthreads();                     // xh free; hsh free (prev e-MFMA done)

        // [C] write h chunk hi/lo + hT ; prefetch next x chunk
#pragma unroll
        for (int r = 0; r < 4; ++r) {
            const int m = mt * 16 + kb * 4 + r;      // chunk-local row
            const int d = nt2 * 16 + ml;             // output feature
            unsigned hi = bf16_rne(hacc[r]);
            float hif = __uint_as_float(hi << 16);
            hsh[m * 72 + d] = (unsigned short)hi;
            hsl[m * 72 + d] = (unsigned short)bf16_rne(hacc[r] - hif);
            hT[d * 264 + c * 32 + m] = (unsigned short)hi;
        }
        if (c < 7) {
            const size_t xb = (size_t)(b * 256 + (c + 1) * 32) * 128;
            xv0 = *(const float4*)&x[xb + (size_t)(t >> 5) * 128 + (t & 31) * 4];
            xv1 = *(const float4*)&x[xb + (size_t)((t + 512) >> 5) * 128 + (t & 31) * 4];
        }
        __syncthreads();                     // hsh ready

        // [D] e-MFMA (waves 0..3): e[32][24] = h_chunk @ Acat^T
        if (wv < 4) {
            const int mt2 = wv & 1, at = wv >> 1;
            f32x4 eacc = {0.f, 0.f, 0.f, 0.f};
#pragma unroll
            for (int ks = 0; ks < 2; ++ks) {
                const int ko = ks * 32 + kb * 8;
                bf16x8 ah = *(const bf16x8*)&hsh[(mt2 * 16 + ml) * 72 + ko];
                bf16x8 al = *(const bf16x8*)&hsl[(mt2 * 16 + ml) * 72 + ko];
                bf16x8 bh = *(const bf16x8*)&Ach[(at * 16 + ml) * 72 + ko];
                bf16x8 bl = *(const bf16x8*)&Acl[(at * 16 + ml) * 72 + ko];
                eacc = __builtin_amdgcn_mfma_f32_16x16x32_bf16(ah, bh, eacc, 0, 0, 0);
                eacc = __builtin_amdgcn_mfma_f32_16x16x32_bf16(ah, bl, eacc, 0, 0, 0);
                eacc = __builtin_amdgcn_mfma_f32_16x16x32_bf16(al, bh, eacc, 0, 0, 0);
            }
#pragma unroll
            for (int r = 0; r < 4; ++r) {
                const int m = mt2 * 16 + kb * 4 + r;
                const int n = at * 16 + ml;
                const int j = c * 32 + m;            // batch-local row
                if (n < 12) {
                    if (j >= i0 && j < i0 + 16)
                        esl[(j - i0) * 12 + n] = (eacc[r] + ab[n]) * L2E;
                } else if (n < 24) {
                    edT[(n - 12) * 260 + j] = eacc[r] * L2E;
                }
            }
        }
        // no barrier: next [A] touches xh only, [D] reads hsh/writes edT
    }
    __syncthreads();                         // hT, edT, esl complete

    // ---- phase 2: masked 12-head softmax (no-max, pre-scaled) ----
    float fm[3][8];
    fm[0][0] = (float)Ma0.x; fm[0][1] = (float)Ma0.y; fm[0][2] = (float)Ma0.z; fm[0][3] = (float)Ma0.w;
    fm[0][4] = (float)Ma1.x; fm[0][5] = (float)Ma1.y; fm[0][6] = (float)Ma1.z; fm[0][7] = (float)Ma1.w;
    fm[1][0] = (float)Mb0.x; fm[1][1] = (float)Mb0.y; fm[1][2] = (float)Mb0.z; fm[1][3] = (float)Mb0.w;
    fm[1][4] = (float)Mb1.x; fm[1][5] = (float)Mb1.y; fm[1][6] = (float)Mb1.z; fm[1][7] = (float)Mb1.w;
    fm[2][0] = (float)Mc0.x; fm[2][1] = (float)Mc0.y; fm[2][2] = (float)Mc0.z; fm[2][3] = (float)Mc0.w;
    fm[2][4] = (float)Mc1.x; fm[2][5] = (float)Mc1.y; fm[2][6] = (float)Mc1.z; fm[2][7] = (float)Mc1.w;

    const float4* ep = (const float4*)&esl[rloc * 12];
    const float4 eA = ep[0], eB = ep[1], eC = ep[2];
    const float e0[12] = {eA.x, eA.y, eA.z, eA.w, eB.x, eB.y, eB.z, eB.w, eC.x, eC.y, eC.z, eC.w};

    float Pacc[8] = {0.f, 0.f, 0.f, 0.f, 0.f, 0.f, 0.f, 0.f};
#pragma unroll
    for (int hh = 0; hh < 12; ++hh) {
        const int grp = hh >> 2;
        const float4* evp = (const float4*)&edT[hh * 260 + 8 * q];
        const float4 ev0 = evp[0], ev1 = evp[1];
        const float evv[8] = {ev0.x, ev0.y, ev0.z, ev0.w, ev1.x, ev1.y, ev1.z, ev1.w};
        float p[8], s = 0.f;
#pragma unroll
        for (int k = 0; k < 8; ++k) {
            float v = e0[hh] + evv[k];
            v = fmaxf(v, 0.01f * v);                     // leaky in log2 domain
            p[k] = __builtin_amdgcn_exp2f(v) * fm[grp][k];
            s += p[k];
        }
#pragma unroll
        for (int off = 16; off >= 1; off >>= 1)
            s += __shfl_xor(s, off);                     // 32-lane group reduce
        const float rinv = __builtin_amdgcn_rcpf(s);
#pragma unroll
        for (int k = 0; k < 8; ++k)
            Pacc[k] += p[k] * rinv;
    }
    {
        uint4 pk;
        pk.x = bf16_rne(Pacc[0]) | (bf16_rne(Pacc[1]) << 16);
        pk.y = bf16_rne(Pacc[2]) | (bf16_rne(Pacc[3]) << 16);
        pk.z = bf16_rne(Pacc[4]) | (bf16_rne(Pacc[5]) << 16);
        pk.w = bf16_rne(Pacc[6]) | (bf16_rne(Pacc[7]) << 16);
        *(uint4*)&Ph[rloc * 264 + 8 * q] = pk;
    }
    __syncthreads();

    // ---- PV: out[16][64] = P[16][256] x hT^T ; K split across wave pairs ----
    const int nt = wv & 3, kh = wv >> 2;
    f32x4 acc = {0.f, 0.f, 0.f, 0.f};
#pragma unroll
    for (int ks = 0; ks < 4; ++ks) {
        const int ko = kh * 128 + ks * 32 + kb * 8;
        bf16x8 bh = *(const bf16x8*)&hT[(nt * 16 + ml) * 264 + ko];
        bf16x8 ah = *(const bf16x8*)&Ph[ml * 264 + ko];
        acc = __builtin_amdgcn_mfma_f32_16x16x32_bf16(ah, bh, acc, 0, 0, 0);
    }
    if (kh == 1) {
#pragma unroll
        for (int r = 0; r < 4; ++r)
            red[nt * 272 + (kb * 4 + r) * 17 + ml] = acc[r];
    }
    __syncthreads();
    if (kh == 0) {
#pragma unroll
        for (int r = 0; r < 4; ++r) {
            const int m = kb * 4 + r;        // 0..15
            const float v = (acc[r] + red[nt * 272 + m * 17 + ml]) * (1.0f / 12.0f);
            out[(size_t)(b * 256 + i0 + m) * 64 + nt * 16 + ml] = v;
        }
    }
}

extern "C" void kernel_launch(void* const* d_in, const int* in_sizes, int n_in,
                              void* d_out, int out_size, void* d_ws, size_t ws_size,
                              hipStream_t stream) {
    const float* x    = (const float*)d_in[0];
    const int*   adj  = (const int*)d_in[1];
    const int*   adji = (const int*)d_in[2];
    const int*   adjo = (const int*)d_in[3];
    const float* W    = (const float*)d_in[4];
    const float* A    = (const float*)d_in[5];
    const float* ab   = (const float*)d_in[6];
    float* out = (float*)d_out;

    fused_gat<<<256, 512, 0, stream>>>(x, adj, adji, adjo, W, A, ab, out);
}